// Round 1
// baseline (31.325 us; speedup 1.0000x reference)
//
#include <hip/hip_runtime.h>

#define NJ   24
#define BLK  256
#define XPAD 25     // LDS row stride for x rows (24 + 1, coprime with 32 banks)
#define JCN  20     // floats per joint-constant record

__global__ __launch_bounds__(BLK)
void poe_kernel(const float* __restrict__ x,
                const float* __restrict__ eta,
                const float* __restrict__ M,
                float* __restrict__ out,
                int nBatch)
{
    __shared__ float sX[BLK * XPAD];
    __shared__ float sJC[NJ * JCN];
    __shared__ float sEM[12];

    const int tid  = threadIdx.x;
    const int base = blockIdx.x * BLK;

    // ---- stage this block's x slab (coalesced dword loads) ----
    const float* xblk = x + (size_t)base * NJ;
    const int lim = (nBatch - base) * NJ;   // valid elements in this block
    #pragma unroll
    for (int i = 0; i < NJ; ++i) {
        int idx = i * BLK + tid;
        float val = (idx < lim) ? xblk[idx] : 0.0f;
        int r = idx / NJ;
        int c = idx - r * NJ;
        sX[r * XPAD + c] = val;
    }

    // ---- per-joint constants (lanes 0..23) ----
    if (tid < NJ) {
        const float w0 = eta[tid*6+0], w1 = eta[tid*6+1], w2 = eta[tid*6+2];
        const float v0 = eta[tid*6+3], v1 = eta[tid*6+4], v2 = eta[tid*6+5];
        float k   = w0*w0 + w1*w1 + w2*w2;
        float c10 = w1*v2 - w2*v1;
        float c11 = w2*v0 - w0*v2;
        float c12 = w0*v1 - w1*v0;
        float* jc = &sJC[tid * JCN];
        jc[0]  = w0;  jc[1]  = w1;  jc[2]  = w2;  jc[3]  = k;
        jc[4]  = v0;  jc[5]  = v1;  jc[6]  = v2;  jc[7]  = w0*w0 - k;   // d0
        jc[8]  = c10; jc[9]  = c11; jc[10] = c12; jc[11] = w1*w1 - k;   // d1
        jc[12] = w1*c12 - w2*c11;                                        // c2 = w x c1
        jc[13] = w2*c10 - w0*c12;
        jc[14] = w0*c11 - w1*c10;
        jc[15] = w2*w2 - k;                                              // d2
        jc[16] = w0*w1; jc[17] = w0*w2; jc[18] = w1*w2; jc[19] = 0.0f;
    }

    // ---- constant tail transform exp(M_se3) (lane 24) ----
    if (tid == NJ) {
        const float w0 = M[0], w1 = M[1], w2 = M[2];
        const float v0 = M[3], v1 = M[4], v2 = M[5];
        float t2 = w0*w0 + w1*w1 + w2*w2;
        bool  sm = (t2 < 1e-12f);
        float t2s = sm ? 1.0f : t2;
        float invt = rsqrtf(t2s);
        float th   = t2s * invt;
        float s, c;
        __sincosf(th, &s, &c);
        float invt2 = invt * invt;
        float A = sm ? 1.0f - t2*(1.0f/6.0f)                 : s * invt;
        float B = sm ? 0.5f - t2*(1.0f/24.0f)                : (1.0f - c) * invt2;
        float C = sm ? (1.0f/6.0f) - t2*(1.0f/120.0f)        : (th - s) * invt2 * invt;
        sEM[0] = 1.0f + B*(w0*w0 - t2);
        sEM[1] = B*w0*w1 - A*w2;
        sEM[2] = B*w0*w2 + A*w1;
        sEM[3] = B*w0*w1 + A*w2;
        sEM[4] = 1.0f + B*(w1*w1 - t2);
        sEM[5] = B*w1*w2 - A*w0;
        sEM[6] = B*w0*w2 - A*w1;
        sEM[7] = B*w1*w2 + A*w0;
        sEM[8] = 1.0f + B*(w2*w2 - t2);
        float c10 = w1*v2 - w2*v1, c11 = w2*v0 - w0*v2, c12 = w0*v1 - w1*v0;
        float c20 = w1*c12 - w2*c11, c21 = w2*c10 - w0*c12, c22 = w0*c11 - w1*c10;
        sEM[9]  = v0 + B*c10 + C*c20;
        sEM[10] = v1 + B*c11 + C*c21;
        sEM[11] = v2 + B*c12 + C*c22;
    }

    __syncthreads();

    // ---- chain the 24 exponentials; T kept as R(3x3)+p(3) in registers ----
    float R00=1.f, R01=0.f, R02=0.f;
    float R10=0.f, R11=1.f, R12=0.f;
    float R20=0.f, R21=0.f, R22=1.f;
    float p0=0.f, p1=0.f, p2=0.f;

    for (int j = 0; j < NJ; ++j) {
        const float* jc = &sJC[j * JCN];
        const float w0 = jc[0],  w1 = jc[1],  w2 = jc[2],  k  = jc[3];
        const float v0 = jc[4],  v1 = jc[5],  v2 = jc[6],  d0 = jc[7];
        const float c10= jc[8],  c11= jc[9],  c12= jc[10], d1 = jc[11];
        const float c20= jc[12], c21= jc[13], c22= jc[14], d2 = jc[15];
        const float ww01 = jc[16], ww02 = jc[17], ww12 = jc[18];

        const float aj = sX[tid * XPAD + j];
        const float a2 = aj * aj;
        const float t2 = a2 * k;
        const bool  sm = (t2 < 1e-12f);
        const float t2s  = sm ? 1.0f : t2;
        const float invt = rsqrtf(t2s);
        const float th   = t2s * invt;
        float s, c;
        __sincosf(th, &s, &c);
        const float invt2 = invt * invt;
        const float A = sm ? 1.0f - t2*(1.0f/6.0f)          : s * invt;
        const float B = sm ? 0.5f - t2*(1.0f/24.0f)         : (1.0f - c) * invt2;
        const float C = sm ? (1.0f/6.0f) - t2*(1.0f/120.0f) : (th - s) * invt2 * invt;

        const float Aa  = A * aj;
        const float Ba2 = B * a2;
        const float Ca3 = C * a2 * aj;

        // E rotation = I + Aa*skew(w_j) + Ba2*(w_j w_j^T - k I)
        const float e00 = 1.0f + Ba2 * d0;
        const float e11 = 1.0f + Ba2 * d1;
        const float e22 = 1.0f + Ba2 * d2;
        const float e01 = Ba2 * ww01 - Aa * w2;
        const float e10 = Ba2 * ww01 + Aa * w2;
        const float e02 = Ba2 * ww02 + Aa * w1;
        const float e20 = Ba2 * ww02 - Aa * w1;
        const float e12 = Ba2 * ww12 - Aa * w0;
        const float e21 = Ba2 * ww12 + Aa * w0;
        // E translation = a*v_j + Ba2*(w_j x v_j) + Ca3*(w_j x (w_j x v_j))
        const float q0 = aj * v0 + Ba2 * c10 + Ca3 * c20;
        const float q1 = aj * v1 + Ba2 * c11 + Ca3 * c21;
        const float q2 = aj * v2 + Ba2 * c12 + Ca3 * c22;

        // T = T * E   (both have bottom row [0 0 0 1])
        const float n00 = R00*e00 + R01*e10 + R02*e20;
        const float n01 = R00*e01 + R01*e11 + R02*e21;
        const float n02 = R00*e02 + R01*e12 + R02*e22;
        const float n10 = R10*e00 + R11*e10 + R12*e20;
        const float n11 = R10*e01 + R11*e11 + R12*e21;
        const float n12 = R10*e02 + R11*e12 + R12*e22;
        const float n20 = R20*e00 + R21*e10 + R22*e20;
        const float n21 = R20*e01 + R21*e11 + R22*e21;
        const float n22 = R20*e02 + R21*e12 + R22*e22;
        p0 += R00*q0 + R01*q1 + R02*q2;
        p1 += R10*q0 + R11*q1 + R12*q2;
        p2 += R20*q0 + R21*q1 + R22*q2;
        R00=n00; R01=n01; R02=n02;
        R10=n10; R11=n11; R12=n12;
        R20=n20; R21=n21; R22=n22;
    }

    // ---- final T = T * exp(M) and store ----
    const float m00=sEM[0], m01=sEM[1], m02=sEM[2];
    const float m10=sEM[3], m11=sEM[4], m12=sEM[5];
    const float m20=sEM[6], m21=sEM[7], m22=sEM[8];
    const float mp0=sEM[9], mp1=sEM[10], mp2=sEM[11];

    const int b = base + tid;
    if (b < nBatch) {
        const float f00 = R00*m00 + R01*m10 + R02*m20;
        const float f01 = R00*m01 + R01*m11 + R02*m21;
        const float f02 = R00*m02 + R01*m12 + R02*m22;
        const float f10 = R10*m00 + R11*m10 + R12*m20;
        const float f11 = R10*m01 + R11*m11 + R12*m21;
        const float f12 = R10*m02 + R11*m12 + R12*m22;
        const float f20 = R20*m00 + R21*m10 + R22*m20;
        const float f21 = R20*m01 + R21*m11 + R22*m21;
        const float f22 = R20*m02 + R21*m12 + R22*m22;
        const float fp0 = R00*mp0 + R01*mp1 + R02*mp2 + p0;
        const float fp1 = R10*mp0 + R11*mp1 + R12*mp2 + p1;
        const float fp2 = R20*mp0 + R21*mp1 + R22*mp2 + p2;

        float4* o = (float4*)(out + (size_t)b * 16);
        o[0] = make_float4(f00, f01, f02, fp0);
        o[1] = make_float4(f10, f11, f12, fp1);
        o[2] = make_float4(f20, f21, f22, fp2);
        o[3] = make_float4(0.0f, 0.0f, 0.0f, 1.0f);
    }
}

extern "C" void kernel_launch(void* const* d_in, const int* in_sizes, int n_in,
                              void* d_out, int out_size, void* d_ws, size_t ws_size,
                              hipStream_t stream)
{
    const float* x   = (const float*)d_in[0];
    const float* eta = (const float*)d_in[1];
    const float* M   = (const float*)d_in[2];
    float* out = (float*)d_out;

    const int nBatch = in_sizes[0] / NJ;
    const int grid   = (nBatch + BLK - 1) / BLK;
    poe_kernel<<<grid, BLK, 0, stream>>>(x, eta, M, out, nBatch);
}

// Round 2
// 29.563 us; speedup vs baseline: 1.0596x; 1.0596x over previous
//
#include <hip/hip_runtime.h>

#define NJ   24
#define BLK  256
#define XPAD 25     // LDS row stride for x rows (24 + 1, coprime with 32 banks)
#define JCF  24     // floats per joint-constant record in ws
#define EMOF (NJ * JCF)   // offset of the 12-float exp(M) record

// ---------------------------------------------------------------------------
// Prep kernel: 1 block. Lanes 0..23 build per-joint constant records, lane 24
// builds exp(M_se3). All written to ws (float), consumed via s_load in main.
// Record layout (24 floats, 16B-aligned):
//  [0..2] w   [3] sqk      [4..6] v   [7]  invsqk
//  [8..10] c1=wxv [11] invk  [12..14] c2=wxc1 [15] invk15
//  [16..18] d_i = w_i^2-k  [19] 0   [20..22] ww01,ww02,ww12 [23] 0
// ---------------------------------------------------------------------------
__global__ void poe_prep(const float* __restrict__ eta,
                         const float* __restrict__ M,
                         float* __restrict__ cst)
{
    const int t = threadIdx.x;
    if (t < NJ) {
        const float w0 = eta[t*6+0], w1 = eta[t*6+1], w2 = eta[t*6+2];
        const float v0 = eta[t*6+3], v1 = eta[t*6+4], v2 = eta[t*6+5];
        const float k  = w0*w0 + w1*w1 + w2*w2;
        const bool  sm = (k < 1e-12f);
        const float invsqk = sm ? 0.0f : rsqrtf(k);
        const float sqk    = k * invsqk;          // sqrt(k), 0 if degenerate
        const float invk   = invsqk * invsqk;
        const float invk15 = invk * invsqk;
        const float c10 = w1*v2 - w2*v1;
        const float c11 = w2*v0 - w0*v2;
        const float c12 = w0*v1 - w1*v0;
        float* r = cst + t * JCF;
        r[0]  = w0;  r[1]  = w1;  r[2]  = w2;  r[3]  = sqk;
        r[4]  = v0;  r[5]  = v1;  r[6]  = v2;  r[7]  = invsqk;
        r[8]  = c10; r[9]  = c11; r[10] = c12; r[11] = invk;
        r[12] = w1*c12 - w2*c11;
        r[13] = w2*c10 - w0*c12;
        r[14] = w0*c11 - w1*c10;
        r[15] = invk15;
        r[16] = w0*w0 - k; r[17] = w1*w1 - k; r[18] = w2*w2 - k; r[19] = 0.0f;
        r[20] = w0*w1; r[21] = w0*w2; r[22] = w1*w2; r[23] = 0.0f;
    } else if (t == NJ) {
        const float w0 = M[0], w1 = M[1], w2 = M[2];
        const float v0 = M[3], v1 = M[4], v2 = M[5];
        const float t2 = w0*w0 + w1*w1 + w2*w2;
        const bool  sm = (t2 < 1e-12f);
        const float t2s  = sm ? 1.0f : t2;
        const float invt = rsqrtf(t2s);
        const float th   = t2s * invt;
        float s, c;
        __sincosf(th, &s, &c);
        const float invt2 = invt * invt;
        const float A = sm ? 1.0f            : s * invt;
        const float B = sm ? 0.5f            : (1.0f - c) * invt2;
        const float C = sm ? (1.0f/6.0f)     : (th - s) * invt2 * invt;
        float* r = cst + EMOF;
        r[0] = 1.0f + B*(w0*w0 - t2);
        r[1] = B*w0*w1 - A*w2;
        r[2] = B*w0*w2 + A*w1;
        r[3] = B*w0*w1 + A*w2;
        r[4] = 1.0f + B*(w1*w1 - t2);
        r[5] = B*w1*w2 - A*w0;
        r[6] = B*w0*w2 - A*w1;
        r[7] = B*w1*w2 + A*w0;
        r[8] = 1.0f + B*(w2*w2 - t2);
        const float c10 = w1*v2 - w2*v1, c11 = w2*v0 - w0*v2, c12 = w0*v1 - w1*v0;
        const float c20 = w1*c12 - w2*c11, c21 = w2*c10 - w0*c12, c22 = w0*c11 - w1*c10;
        r[9]  = v0 + B*c10 + C*c20;
        r[10] = v1 + B*c11 + C*c21;
        r[11] = v2 + B*c12 + C*c22;
    }
}

// ---------------------------------------------------------------------------
// Main kernel: one thread per batch row. x staged through LDS for coalescing;
// joint constants arrive via scalar loads (uniform address) -> SGPRs.
// Signed-angle form: phi = a*sqrt(k); A*a = sin(phi)/sqrt(k);
// B*a^2 = (1-cos(phi))/k; C*a^3 = (phi-sin(phi))/k^1.5  (all even in sign).
// ---------------------------------------------------------------------------
__global__ __launch_bounds__(BLK)
void poe_kernel(const float* __restrict__ x,
                const float* __restrict__ cst,
                float* __restrict__ out,
                int nBatch)
{
    __shared__ float sX[BLK * XPAD];

    const int tid  = threadIdx.x;
    const int base = blockIdx.x * BLK;

    // ---- stage this block's x slab (coalesced dword loads) ----
    const float* xblk = x + (size_t)base * NJ;
    const int lim = (nBatch - base) * NJ;
    #pragma unroll
    for (int i = 0; i < NJ; ++i) {
        int idx = i * BLK + tid;
        float val = (idx < lim) ? xblk[idx] : 0.0f;
        int r = idx / NJ;
        int c = idx - r * NJ;
        sX[r * XPAD + c] = val;
    }
    __syncthreads();

    float R00=1.f, R01=0.f, R02=0.f;
    float R10=0.f, R11=1.f, R12=0.f;
    float R20=0.f, R21=0.f, R22=1.f;
    float p0=0.f, p1=0.f, p2=0.f;

    #pragma unroll
    for (int j = 0; j < NJ; ++j) {
        const float* jc = cst + j * JCF;   // uniform address -> s_load
        const float w0 = jc[0],  w1 = jc[1],  w2 = jc[2],  sqk    = jc[3];
        const float v0 = jc[4],  v1 = jc[5],  v2 = jc[6],  invsqk = jc[7];
        const float c10= jc[8],  c11= jc[9],  c12= jc[10], invk   = jc[11];
        const float c20= jc[12], c21= jc[13], c22= jc[14], invk15 = jc[15];
        const float d0 = jc[16], d1 = jc[17], d2 = jc[18];
        const float ww01 = jc[20], ww02 = jc[21], ww12 = jc[22];

        const float a   = sX[tid * XPAD + j];
        const float phi = a * sqk;
        float s, c;
        __sincosf(phi, &s, &c);
        const float Aa  = s * invsqk;
        const float Ba2 = fmaf(-c, invk, invk);        // (1-cos)/k
        const float Ca3 = (phi - s) * invk15;          // (phi-sin)/k^1.5

        // E rotation = I + Aa*skew(w) + Ba2*(w w^T - k I)
        const float t01 = Ba2 * ww01;
        const float t02 = Ba2 * ww02;
        const float t12 = Ba2 * ww12;
        const float e00 = fmaf(Ba2, d0, 1.0f);
        const float e11 = fmaf(Ba2, d1, 1.0f);
        const float e22 = fmaf(Ba2, d2, 1.0f);
        const float e01 = fmaf(-Aa, w2, t01);
        const float e10 = fmaf( Aa, w2, t01);
        const float e02 = fmaf( Aa, w1, t02);
        const float e20 = fmaf(-Aa, w1, t02);
        const float e12 = fmaf(-Aa, w0, t12);
        const float e21 = fmaf( Aa, w0, t12);
        // E translation
        const float q0 = fmaf(a, v0, fmaf(Ba2, c10, Ca3 * c20));
        const float q1 = fmaf(a, v1, fmaf(Ba2, c11, Ca3 * c21));
        const float q2 = fmaf(a, v2, fmaf(Ba2, c12, Ca3 * c22));

        // T = T * E
        const float n00 = fmaf(R00,e00, fmaf(R01,e10, R02*e20));
        const float n01 = fmaf(R00,e01, fmaf(R01,e11, R02*e21));
        const float n02 = fmaf(R00,e02, fmaf(R01,e12, R02*e22));
        const float n10 = fmaf(R10,e00, fmaf(R11,e10, R12*e20));
        const float n11 = fmaf(R10,e01, fmaf(R11,e11, R12*e21));
        const float n12 = fmaf(R10,e02, fmaf(R11,e12, R12*e22));
        const float n20 = fmaf(R20,e00, fmaf(R21,e10, R22*e20));
        const float n21 = fmaf(R20,e01, fmaf(R21,e11, R22*e21));
        const float n22 = fmaf(R20,e02, fmaf(R21,e12, R22*e22));
        p0 = fmaf(R00,q0, fmaf(R01,q1, fmaf(R02,q2, p0)));
        p1 = fmaf(R10,q0, fmaf(R11,q1, fmaf(R12,q2, p1)));
        p2 = fmaf(R20,q0, fmaf(R21,q1, fmaf(R22,q2, p2)));
        R00=n00; R01=n01; R02=n02;
        R10=n10; R11=n11; R12=n12;
        R20=n20; R21=n21; R22=n22;
    }

    // ---- final T = T * exp(M) and store ----
    const float* em = cst + EMOF;          // uniform -> s_load
    const float m00=em[0], m01=em[1], m02=em[2];
    const float m10=em[3], m11=em[4], m12=em[5];
    const float m20=em[6], m21=em[7], m22=em[8];
    const float mp0=em[9], mp1=em[10], mp2=em[11];

    const int b = base + tid;
    if (b < nBatch) {
        const float f00 = fmaf(R00,m00, fmaf(R01,m10, R02*m20));
        const float f01 = fmaf(R00,m01, fmaf(R01,m11, R02*m21));
        const float f02 = fmaf(R00,m02, fmaf(R01,m12, R02*m22));
        const float f10 = fmaf(R10,m00, fmaf(R11,m10, R12*m20));
        const float f11 = fmaf(R10,m01, fmaf(R11,m11, R12*m21));
        const float f12 = fmaf(R10,m02, fmaf(R11,m12, R12*m22));
        const float f20 = fmaf(R20,m00, fmaf(R21,m10, R22*m20));
        const float f21 = fmaf(R20,m01, fmaf(R21,m11, R22*m21));
        const float f22 = fmaf(R20,m02, fmaf(R21,m12, R22*m22));
        const float fp0 = fmaf(R00,mp0, fmaf(R01,mp1, fmaf(R02,mp2, p0)));
        const float fp1 = fmaf(R10,mp0, fmaf(R11,mp1, fmaf(R12,mp2, p1)));
        const float fp2 = fmaf(R20,mp0, fmaf(R21,mp1, fmaf(R22,mp2, p2)));

        float4* o = (float4*)(out + (size_t)b * 16);
        o[0] = make_float4(f00, f01, f02, fp0);
        o[1] = make_float4(f10, f11, f12, fp1);
        o[2] = make_float4(f20, f21, f22, fp2);
        o[3] = make_float4(0.0f, 0.0f, 0.0f, 1.0f);
    }
}

extern "C" void kernel_launch(void* const* d_in, const int* in_sizes, int n_in,
                              void* d_out, int out_size, void* d_ws, size_t ws_size,
                              hipStream_t stream)
{
    const float* x   = (const float*)d_in[0];
    const float* eta = (const float*)d_in[1];
    const float* M   = (const float*)d_in[2];
    float* out = (float*)d_out;
    float* cst = (float*)d_ws;

    const int nBatch = in_sizes[0] / NJ;
    const int grid   = (nBatch + BLK - 1) / BLK;

    poe_prep<<<1, 64, 0, stream>>>(eta, M, cst);
    poe_kernel<<<grid, BLK, 0, stream>>>(x, cst, out, nBatch);
}